// Round 1
// baseline (190.862 us; speedup 1.0000x reference)
//
#include <hip/hip_runtime.h>
#include <hip/hip_bf16.h>
#include <cmath>

// Problem constants
#define BATCH 8
#define NH 8
#define BH 64          // BATCH*NH
#define SEQ 1024
#define DH 64          // head dim
#define NM 64          // modes

// ws layout (floats):
//  P  : [inp 2][thalf 2][bh 64][c 2][m 64][d 64]  = 4,194,304 floats (fwd-DFT partials)
//  C2 : [bh 64][q 64][j 64][c 2]                  =   524,288 floats
#define P_PLANE 4096   // 64m*64d
#define C2_OFF  4194304

// ---------------------------------------------------------------------------
// Kernel 1: partial forward DFT. grid = (bh, input, t-half) = 256 blocks.
// Each block: all 64 modes x 64 d over 512 time samples (partial sum).
// Thread tile: 2 modes x 8 d. Twiddles: per-thread rotators, refreshed each
// 64-sample chunk from exact integer phase via sincospif.
// ---------------------------------------------------------------------------
__global__ __launch_bounds__(256) void k_dft(const float* __restrict__ q,
                                             const float* __restrict__ k,
                                             float* __restrict__ P) {
  const int bid = blockIdx.x;
  const int bh = bid & 63;
  const int inp = (bid >> 6) & 1;
  const int th = bid >> 7;
  const float* x = (inp ? k : q) + (size_t)bh * (SEQ * DH);  // [t][d]

  __shared__ float xs[64][64];
  const int tid = threadIdx.x;
  const int dg = tid & 7;   // 8 d-groups of 8
  const int mg = tid >> 3;  // 32 m-groups of 2
  const int d0 = dg * 8;

  float accr[2][8] = {{0.f}}, acci[2][8] = {{0.f}};

  // rotator step per mode: e^{-2*pi*i*m/1024}
  float stepc[2], steps_[2];
#pragma unroll
  for (int mi = 0; mi < 2; ++mi) {
    float ph = (float)(mg * 2 + mi) * (1.0f / 512.0f);
    stepc[mi] = cospif(ph);
    steps_[mi] = -sinpif(ph);
  }

  for (int ch = 0; ch < 8; ++ch) {
    const int t0g = th * 512 + ch * 64;
    // stage 64t x 64d chunk
    const float4* src = reinterpret_cast<const float4*>(x + (size_t)t0g * DH);
    float4* dst = reinterpret_cast<float4*>(&xs[0][0]);
#pragma unroll
    for (int i = 0; i < 4; ++i) dst[tid + i * 256] = src[tid + i * 256];
    __syncthreads();

    // fresh twiddles for chunk start: e^{-2*pi*i*m*t0g/1024}
    float wr[2], wi[2];
#pragma unroll
    for (int mi = 0; mi < 2; ++mi) {
      int m = mg * 2 + mi;
      int p0 = (m * t0g) & 1023;
      float ph = (float)p0 * (1.0f / 512.0f);
      wr[mi] = cospif(ph);
      wi[mi] = -sinpif(ph);
    }

#pragma unroll 4
    for (int t = 0; t < 64; ++t) {
      float4 a = *reinterpret_cast<const float4*>(&xs[t][d0]);
      float4 b = *reinterpret_cast<const float4*>(&xs[t][d0 + 4]);
      float xv[8] = {a.x, a.y, a.z, a.w, b.x, b.y, b.z, b.w};
#pragma unroll
      for (int mi = 0; mi < 2; ++mi) {
        float cwr = wr[mi], cwi = wi[mi];
#pragma unroll
        for (int di = 0; di < 8; ++di) {
          accr[mi][di] = fmaf(cwr, xv[di], accr[mi][di]);
          acci[mi][di] = fmaf(cwi, xv[di], acci[mi][di]);
        }
        float nr = cwr * stepc[mi] - cwi * steps_[mi];
        float ni = cwr * steps_[mi] + cwi * stepc[mi];
        wr[mi] = nr; wi[mi] = ni;
      }
    }
    __syncthreads();
  }

  // write partials: P[inp][th][bh][c][m][d]
  const size_t base = ((((size_t)inp * 2 + th) * 64 + bh) * 2) * P_PLANE;
#pragma unroll
  for (int mi = 0; mi < 2; ++mi) {
    int m = mg * 2 + mi;
    float* pr = P + base + (size_t)m * 64 + d0;
    float* pi = P + base + P_PLANE + (size_t)m * 64 + d0;
    *reinterpret_cast<float4*>(pr)     = make_float4(accr[mi][0], accr[mi][1], accr[mi][2], accr[mi][3]);
    *reinterpret_cast<float4*>(pr + 4) = make_float4(accr[mi][4], accr[mi][5], accr[mi][6], accr[mi][7]);
    *reinterpret_cast<float4*>(pi)     = make_float4(acci[mi][0], acci[mi][1], acci[mi][2], acci[mi][3]);
    *reinterpret_cast<float4*>(pi + 4) = make_float4(acci[mi][4], acci[mi][5], acci[mi][6], acci[mi][7]);
  }
}

// stable complex tanh: tanh(x+iy) = (sinh2x + i sin2y)/(cosh2x + cos2y)
__device__ __forceinline__ void ctanh_f(float x, float y, float& rr, float& ri) {
  float a = 2.0f * x, b = 2.0f * y;
  if (fabsf(a) > 20.0f) {
    rr = (a > 0.0f) ? 1.0f : -1.0f;
    ri = 0.0f;
  } else {
    float ea = expf(a), ena = expf(-a);
    float sb, cb;
    sincosf(b, &sb, &cb);
    float den = 0.5f * (ea + ena) + cb;
    rr = 0.5f * (ea - ena) / den;
    ri = sb / den;
  }
}

// ---------------------------------------------------------------------------
// Kernel 2: scores -> ctanh -> context -> per-mode weight matvec.
// grid = (bh, q-quarter) = 256 blocks. All reductions are over d/k/i, so a
// q-split is exact. LDS padded (67 / 17) to kill bank conflicts.
// ---------------------------------------------------------------------------
__global__ __launch_bounds__(256) void k_mid(const float* __restrict__ P,
                                             const float* __restrict__ wre,
                                             const float* __restrict__ wim,
                                             float* __restrict__ C2) {
  __shared__ float Kr[64][67], Ki[64][67];
  __shared__ float Qr[16][67], Qi[16][67];
  __shared__ float Ar[16][67], Ai[16][67];
  __shared__ float C1r[64][17], C1i[64][17];

  const int tid = threadIdx.x;
  const int bh = blockIdx.x >> 2;
  const int qq = blockIdx.x & 3;
  const int h = bh & 7;

  const size_t pq0 = (((size_t)0 * 2 + 0) * 64 + bh) * 2 * P_PLANE;
  const size_t pq1 = (((size_t)0 * 2 + 1) * 64 + bh) * 2 * P_PLANE;
  const size_t pk0 = (((size_t)1 * 2 + 0) * 64 + bh) * 2 * P_PLANE;
  const size_t pk1 = (((size_t)1 * 2 + 1) * 64 + bh) * 2 * P_PLANE;

  for (int idx = tid; idx < 4096; idx += 256) {
    int kk = idx >> 6, dd = idx & 63;
    Kr[kk][dd] = P[pk0 + idx] + P[pk1 + idx];
    Ki[kk][dd] = P[pk0 + P_PLANE + idx] + P[pk1 + P_PLANE + idx];
  }
  for (int idx = tid; idx < 1024; idx += 256) {
    int qi2 = idx >> 6, dd = idx & 63;
    int m = qq * 16 + qi2;
    Qr[qi2][dd] = P[pq0 + m * 64 + dd] + P[pq1 + m * 64 + dd];
    Qi[qi2][dd] = P[pq0 + P_PLANE + m * 64 + dd] + P[pq1 + P_PLANE + m * 64 + dd];
  }
  __syncthreads();

  // scores S[q][k] = sum_d Q[q][d]*K[k][d]  (complex, no conj) -> ctanh
  {
    const int q = tid >> 4, k0 = (tid & 15) * 4;
    float sr[4] = {0.f}, si[4] = {0.f};
    for (int d = 0; d < 64; ++d) {
      float qr = Qr[q][d], qi = Qi[q][d];
#pragma unroll
      for (int j = 0; j < 4; ++j) {
        float kr = Kr[k0 + j][d], ki = Ki[k0 + j][d];
        sr[j] = fmaf(qr, kr, sr[j]); sr[j] = fmaf(-qi, ki, sr[j]);
        si[j] = fmaf(qr, ki, si[j]); si[j] = fmaf(qi, kr, si[j]);
      }
    }
#pragma unroll
    for (int j = 0; j < 4; ++j) {
      float rr, ri;
      ctanh_f(sr[j], si[j], rr, ri);
      Ar[q][k0 + j] = rr;
      Ai[q][k0 + j] = ri;
    }
  }
  __syncthreads();

  // C1[d][q] = sum_k A[q][k]*K[k][d]   (complex*complex)
  {
    const int q = tid >> 4, d0 = (tid & 15) * 4;
    float cr[4] = {0.f}, ci[4] = {0.f};
    for (int kk = 0; kk < 64; ++kk) {
      float ar = Ar[q][kk], ai = Ai[q][kk];
#pragma unroll
      for (int j = 0; j < 4; ++j) {
        float kr = Kr[kk][d0 + j], ki = Ki[kk][d0 + j];
        cr[j] = fmaf(ar, kr, cr[j]); cr[j] = fmaf(-ai, ki, cr[j]);
        ci[j] = fmaf(ar, ki, ci[j]); ci[j] = fmaf(ai, kr, ci[j]);
      }
    }
#pragma unroll
    for (int j = 0; j < 4; ++j) { C1r[d0 + j][q] = cr[j]; C1i[d0 + j][q] = ci[j]; }
  }
  __syncthreads();

  // C2[q][j] = sum_i C1[i][q] * (wre+i*wim)[h][i][j][q]
  {
    const int ql = tid & 15, j0 = (tid >> 4) * 4;
    const int qg = qq * 16 + ql;
    float ar[4] = {0.f}, ai[4] = {0.f};
    for (int i = 0; i < 64; ++i) {
      float c1r = C1r[i][ql], c1i = C1i[i][ql];
      const size_t wb = (((size_t)h * 64 + i) * 64 + j0) * 64 + qg;
#pragma unroll
      for (int j = 0; j < 4; ++j) {
        float wr = wre[wb + (size_t)j * 64];
        float wi = wim[wb + (size_t)j * 64];
        ar[j] = fmaf(c1r, wr, ar[j]); ar[j] = fmaf(-c1i, wi, ar[j]);
        ai[j] = fmaf(c1r, wi, ai[j]); ai[j] = fmaf(c1i, wr, ai[j]);
      }
    }
#pragma unroll
    for (int j = 0; j < 4; ++j) {
      size_t o = (((size_t)bh * 64 + qg) * 64 + (j0 + j)) * 2;
      C2[o] = ar[j];
      C2[o + 1] = ai[j];
    }
  }
}

// ---------------------------------------------------------------------------
// Kernel 3: inverse partial DFT (64 modes -> 1024 time samples).
// grid = (bh, t-chunk of 128) = 512 blocks. Thread tile 8j x 4t, per-t
// rotators over the mode loop. Scale folds 1/(512*512*1024) and the x2
// Hermitian factor for modes >= 1; imag of mode 0 is dropped (c2r).
// ---------------------------------------------------------------------------
__global__ __launch_bounds__(256) void k_idft(const float* __restrict__ C2,
                                              float* __restrict__ out) {
  __shared__ float Cr[64][68], Ci[64][68];
  const int tid = threadIdx.x;
  const int bh = blockIdx.x >> 3;
  const int tc = blockIdx.x & 7;
  const float s = 1.0f / (512.0f * 512.0f * 1024.0f);

  for (int idx = tid; idx < 4096; idx += 256) {
    int m = idx >> 6, j = idx & 63;
    float f = (m == 0) ? s : 2.0f * s;
    Cr[m][j] = f * C2[((size_t)bh * 4096 + idx) * 2];
    Ci[m][j] = f * C2[((size_t)bh * 4096 + idx) * 2 + 1];
  }
  __syncthreads();

  const int tt = tid & 31, jg = tid >> 5;
  const int t0 = tc * 128 + tt * 4, j0 = jg * 8;

  float wc[4], wsn[4], sc[4], ss[4];
#pragma unroll
  for (int kk = 0; kk < 4; ++kk) {
    float ph = (float)((t0 + kk) & 1023) * (1.0f / 512.0f);
    sc[kk] = cospif(ph);   // step e^{+2*pi*i*t/1024}
    ss[kk] = sinpif(ph);
    wc[kk] = 1.0f;         // m = 0
    wsn[kk] = 0.0f;
  }

  float acc[4][8] = {{0.f}};
  for (int m = 0; m < 64; ++m) {
    float4 c0 = *reinterpret_cast<const float4*>(&Cr[m][j0]);
    float4 c1 = *reinterpret_cast<const float4*>(&Cr[m][j0 + 4]);
    float4 e0 = *reinterpret_cast<const float4*>(&Ci[m][j0]);
    float4 e1 = *reinterpret_cast<const float4*>(&Ci[m][j0 + 4]);
    float crv[8] = {c0.x, c0.y, c0.z, c0.w, c1.x, c1.y, c1.z, c1.w};
    float civ[8] = {e0.x, e0.y, e0.z, e0.w, e1.x, e1.y, e1.z, e1.w};
#pragma unroll
    for (int kk = 0; kk < 4; ++kk) {
      float cw = wc[kk], sw = wsn[kk];
#pragma unroll
      for (int jj = 0; jj < 8; ++jj) {
        acc[kk][jj] = fmaf(crv[jj], cw, acc[kk][jj]);
        acc[kk][jj] = fmaf(-civ[jj], sw, acc[kk][jj]);
      }
      float nr = cw * sc[kk] - sw * ss[kk];
      float ni = cw * ss[kk] + sw * sc[kk];
      wc[kk] = nr; wsn[kk] = ni;
    }
  }

#pragma unroll
  for (int jj = 0; jj < 8; ++jj) {
    float4 v = make_float4(acc[0][jj], acc[1][jj], acc[2][jj], acc[3][jj]);
    *reinterpret_cast<float4*>(&out[(size_t)bh * 65536 + (size_t)(j0 + jj) * 1024 + t0]) = v;
  }
}

extern "C" void kernel_launch(void* const* d_in, const int* in_sizes, int n_in,
                              void* d_out, int out_size, void* d_ws, size_t ws_size,
                              hipStream_t stream) {
  const float* q   = (const float*)d_in[0];
  const float* k   = (const float*)d_in[1];
  // d_in[2] = value, unused by the reference forward
  const float* wre = (const float*)d_in[3];
  const float* wim = (const float*)d_in[4];
  float* out = (float*)d_out;
  float* ws  = (float*)d_ws;

  float* P  = ws;
  float* C2 = ws + C2_OFF;

  k_dft <<<256, 256, 0, stream>>>(q, k, P);
  k_mid <<<256, 256, 0, stream>>>(P, wre, wim, C2);
  k_idft<<<512, 256, 0, stream>>>(C2, out);
}

// Round 2
// 178.138 us; speedup vs baseline: 1.0714x; 1.0714x over previous
//
#include <hip/hip_runtime.h>
#include <hip/hip_bf16.h>
#include <cmath>

// Problem constants
#define BATCH 8
#define NH 8
#define BH 64          // BATCH*NH
#define SEQ 1024
#define DH 64          // head dim
#define NM 64          // modes

// ws layout (floats):
//  P   : [inp 2][tq 4][bh 64][c 2][m 64][d 64] = 4,194,304 floats (fwd-DFT partials)
//  C1r : [bh 64][i 64][q 64]                   =   262,144
//  C1i : [bh 64][i 64][q 64]                   =   262,144
//  C2  : [bh 64][j 64][m 64][c 2]              =   524,288
#define P_PLANE 4096   // 64m*64d
#define P_FLOATS (2*4*64*2*4096)
#define C1R_OFF  P_FLOATS
#define C1I_OFF  (C1R_OFF + 64*64*64)
#define C2_OFF   (C1I_OFF + 64*64*64)

// ---------------------------------------------------------------------------
// Kernel 1: partial forward DFT. grid = (bh 64, input 2, t-quarter 4) = 512
// blocks x 256 thr = 2048 waves = 8 waves/CU (2 blocks/CU).
// Thread tile: 1 mode x 16 d (rotator overhead 4 ops vs 32 fma).
// ---------------------------------------------------------------------------
__global__ __launch_bounds__(256) void k_dft(const float* __restrict__ q,
                                             const float* __restrict__ k,
                                             float* __restrict__ P) {
  const int bid = blockIdx.x;
  const int bh = bid & 63;
  const int inp = (bid >> 6) & 1;
  const int tq = bid >> 7;  // 0..3, 256 samples each
  const float* x = (inp ? k : q) + (size_t)bh * (SEQ * DH);  // [t][d]

  __shared__ float xs[64][64];
  const int tid = threadIdx.x;
  const int m = tid >> 2;       // 0..63
  const int d0 = (tid & 3) * 16;

  float accr[16] = {0.f}, acci[16] = {0.f};

  // rotator step: e^{-2*pi*i*m/1024}
  const float phs = (float)m * (1.0f / 512.0f);
  const float stepc = cospif(phs);
  const float steps = -sinpif(phs);

  for (int ch = 0; ch < 4; ++ch) {
    const int t0g = tq * 256 + ch * 64;
    const float4* src = reinterpret_cast<const float4*>(x + (size_t)t0g * DH);
    float4* dst = reinterpret_cast<float4*>(&xs[0][0]);
#pragma unroll
    for (int i = 0; i < 4; ++i) dst[tid + i * 256] = src[tid + i * 256];
    __syncthreads();

    // fresh twiddle at chunk start: e^{-2*pi*i*m*t0g/1024}
    const int p0 = (m * t0g) & 1023;
    const float ph0 = (float)p0 * (1.0f / 512.0f);
    float wr = cospif(ph0);
    float wi = -sinpif(ph0);

#pragma unroll 4
    for (int t = 0; t < 64; ++t) {
      float4 a = *reinterpret_cast<const float4*>(&xs[t][d0]);
      float4 b = *reinterpret_cast<const float4*>(&xs[t][d0 + 4]);
      float4 c = *reinterpret_cast<const float4*>(&xs[t][d0 + 8]);
      float4 e = *reinterpret_cast<const float4*>(&xs[t][d0 + 12]);
      float xv[16] = {a.x, a.y, a.z, a.w, b.x, b.y, b.z, b.w,
                      c.x, c.y, c.z, c.w, e.x, e.y, e.z, e.w};
#pragma unroll
      for (int di = 0; di < 16; ++di) {
        accr[di] = fmaf(wr, xv[di], accr[di]);
        acci[di] = fmaf(wi, xv[di], acci[di]);
      }
      float nr = wr * stepc - wi * steps;
      float ni = wr * steps + wi * stepc;
      wr = nr; wi = ni;
    }
    __syncthreads();
  }

  // P[inp][tq][bh][c][m][d]
  const size_t base = ((((size_t)inp * 4 + tq) * 64 + bh) * 2) * P_PLANE;
  float* pr = P + base + (size_t)m * 64 + d0;
  float* pi = P + base + P_PLANE + (size_t)m * 64 + d0;
#pragma unroll
  for (int i = 0; i < 4; ++i) {
    *reinterpret_cast<float4*>(pr + i * 4) =
        make_float4(accr[i * 4], accr[i * 4 + 1], accr[i * 4 + 2], accr[i * 4 + 3]);
    *reinterpret_cast<float4*>(pi + i * 4) =
        make_float4(acci[i * 4], acci[i * 4 + 1], acci[i * 4 + 2], acci[i * 4 + 3]);
  }
}

// stable complex tanh: tanh(x+iy) = (sinh2x + i sin2y)/(cosh2x + cos2y)
__device__ __forceinline__ void ctanh_f(float x, float y, float& rr, float& ri) {
  float a = 2.0f * x, b = 2.0f * y;
  if (fabsf(a) > 20.0f) {
    rr = (a > 0.0f) ? 1.0f : -1.0f;
    ri = 0.0f;
  } else {
    float ea = expf(a), ena = expf(-a);
    float sb, cb;
    sincosf(b, &sb, &cb);
    float den = 0.5f * (ea + ena) + cb;
    rr = 0.5f * (ea - ena) / den;
    ri = sb / den;
  }
}

// ---------------------------------------------------------------------------
// Kernel 2a: scores -> ctanh -> context -> C1. grid = (bh, q-quarter) = 256
// blocks. Reductions are over d/k, so q-split is exact.
// C1 written q-innermost for k_mid_b's coalesced lane=q loads.
// ---------------------------------------------------------------------------
__global__ __launch_bounds__(256) void k_mid_a(const float* __restrict__ P,
                                               float* __restrict__ C1r,
                                               float* __restrict__ C1i) {
  __shared__ float Kr[64][67], Ki[64][67];
  __shared__ float Qr[16][67], Qi[16][67];
  __shared__ float Ar[16][67], Ai[16][67];
  __shared__ float C1rs[64][17], C1is[64][17];

  const int tid = threadIdx.x;
  const int bh = blockIdx.x >> 2;
  const int qq = blockIdx.x & 3;

  // P[inp][tq][bh][c][m][d]
  size_t pq[4], pk[4];
#pragma unroll
  for (int t = 0; t < 4; ++t) {
    pq[t] = (((size_t)(0 * 4 + t) * 64 + bh) * 2) * P_PLANE;
    pk[t] = (((size_t)(1 * 4 + t) * 64 + bh) * 2) * P_PLANE;
  }

  for (int idx = tid; idx < 4096; idx += 256) {
    int kk = idx >> 6, dd = idx & 63;
    float r = 0.f, im = 0.f;
#pragma unroll
    for (int t = 0; t < 4; ++t) {
      r += P[pk[t] + idx];
      im += P[pk[t] + P_PLANE + idx];
    }
    Kr[kk][dd] = r; Ki[kk][dd] = im;
  }
  for (int idx = tid; idx < 1024; idx += 256) {
    int qi2 = idx >> 6, dd = idx & 63;
    int mm = qq * 16 + qi2;
    float r = 0.f, im = 0.f;
#pragma unroll
    for (int t = 0; t < 4; ++t) {
      r += P[pq[t] + mm * 64 + dd];
      im += P[pq[t] + P_PLANE + mm * 64 + dd];
    }
    Qr[qi2][dd] = r; Qi[qi2][dd] = im;
  }
  __syncthreads();

  // scores S[q][k] = sum_d Q[q][d]*K[k][d]  (complex, no conj) -> ctanh
  {
    const int q = tid >> 4, k0 = (tid & 15) * 4;
    float sr[4] = {0.f}, si[4] = {0.f};
    for (int d = 0; d < 64; ++d) {
      float qr = Qr[q][d], qi = Qi[q][d];
#pragma unroll
      for (int j = 0; j < 4; ++j) {
        float kr = Kr[k0 + j][d], ki = Ki[k0 + j][d];
        sr[j] = fmaf(qr, kr, sr[j]); sr[j] = fmaf(-qi, ki, sr[j]);
        si[j] = fmaf(qr, ki, si[j]); si[j] = fmaf(qi, kr, si[j]);
      }
    }
#pragma unroll
    for (int j = 0; j < 4; ++j) {
      float rr, ri;
      ctanh_f(sr[j], si[j], rr, ri);
      Ar[q][k0 + j] = rr;
      Ai[q][k0 + j] = ri;
    }
  }
  __syncthreads();

  // C1[d][q] = sum_k A[q][k]*K[k][d]
  {
    const int q = tid >> 4, d0 = (tid & 15) * 4;
    float cr[4] = {0.f}, ci[4] = {0.f};
    for (int kk = 0; kk < 64; ++kk) {
      float ar = Ar[q][kk], ai = Ai[q][kk];
#pragma unroll
      for (int j = 0; j < 4; ++j) {
        float kr = Kr[kk][d0 + j], ki = Ki[kk][d0 + j];
        cr[j] = fmaf(ar, kr, cr[j]); cr[j] = fmaf(-ai, ki, cr[j]);
        ci[j] = fmaf(ar, ki, ci[j]); ci[j] = fmaf(ai, kr, ci[j]);
      }
    }
#pragma unroll
    for (int j = 0; j < 4; ++j) { C1rs[d0 + j][q] = cr[j]; C1is[d0 + j][q] = ci[j]; }
  }
  __syncthreads();

  // write C1[bh][i][qglobal], coalesced 16-float runs
  for (int idx = tid; idx < 1024; idx += 256) {
    int i = idx >> 4, ql = idx & 15;
    size_t o = ((size_t)bh * 64 + i) * 64 + qq * 16 + ql;
    C1r[o] = C1rs[i][ql];
    C1i[o] = C1is[i][ql];
  }
}

// ---------------------------------------------------------------------------
// Kernel 2b: C2[b,h,j,q] = sum_i C1[b,h,i,q] * (wre+i*wim)[h,i,j,q]
// lane = q -> weight loads w[h][i][j][0..63] are 256B coalesced (q innermost).
// grid = (h 8, j 64, b-quarter 4) = 2048 one-wave blocks = 8 waves/CU.
// ---------------------------------------------------------------------------
__global__ __launch_bounds__(64) void k_mid_b(const float* __restrict__ C1r,
                                              const float* __restrict__ C1i,
                                              const float* __restrict__ wre,
                                              const float* __restrict__ wim,
                                              float* __restrict__ C2) {
  const int bid = blockIdx.x;
  const int j = bid & 63;
  const int h = (bid >> 6) & 7;
  const int bq = bid >> 9;       // 0..3 -> batches {2bq, 2bq+1}
  const int lane = threadIdx.x;  // q

  float ar[2] = {0.f, 0.f}, ai[2] = {0.f, 0.f};
  for (int i = 0; i < 64; ++i) {
    size_t wo = (((size_t)h * 64 + i) * 64 + j) * 64 + lane;
    float wr = wre[wo], wi = wim[wo];
#pragma unroll
    for (int bb = 0; bb < 2; ++bb) {
      int bh = (bq * 2 + bb) * 8 + h;
      size_t co = ((size_t)bh * 64 + i) * 64 + lane;
      float c1r = C1r[co], c1i = C1i[co];
      ar[bb] = fmaf(c1r, wr, ar[bb]); ar[bb] = fmaf(-c1i, wi, ar[bb]);
      ai[bb] = fmaf(c1r, wi, ai[bb]); ai[bb] = fmaf(c1i, wr, ai[bb]);
    }
  }
#pragma unroll
  for (int bb = 0; bb < 2; ++bb) {
    int bh = (bq * 2 + bb) * 8 + h;
    // C2[bh][j][m][2]
    *reinterpret_cast<float2*>(&C2[(((size_t)bh * 64 + j) * 64 + lane) * 2]) =
        make_float2(ar[bb], ai[bb]);
  }
}

// ---------------------------------------------------------------------------
// Kernel 3: inverse partial DFT. grid = (bh, 16 t-chunks of 64) = 1024 blocks
// = 16 waves/CU. Thread tile 2t x 8j. Scale folds 1/(512*512*1024) and the
// x2 Hermitian factor for modes >= 1; mode-0 imag drops via sin(0)=0.
// ---------------------------------------------------------------------------
__global__ __launch_bounds__(256) void k_idft(const float* __restrict__ C2,
                                              float* __restrict__ out) {
  __shared__ float Cr[64][68], Ci[64][68];
  const int tid = threadIdx.x;
  const int bh = blockIdx.x >> 4;
  const int tc = blockIdx.x & 15;
  const float s = 1.0f / (512.0f * 512.0f * 1024.0f);

  for (int idx = tid; idx < 4096; idx += 256) {
    int j = idx >> 6, m = idx & 63;
    float f = (m == 0) ? s : 2.0f * s;
    float2 c = *reinterpret_cast<const float2*>(&C2[(((size_t)bh * 64 + j) * 64 + m) * 2]);
    Cr[m][j] = f * c.x;
    Ci[m][j] = f * c.y;
  }
  __syncthreads();

  const int tg = tid & 31, jg = tid >> 5;
  const int t0 = tc * 64 + tg * 2, j0 = jg * 8;

  float sc[2], ss[2], wc[2], wsn[2];
#pragma unroll
  for (int kk = 0; kk < 2; ++kk) {
    float ph = (float)((t0 + kk) & 1023) * (1.0f / 512.0f);
    sc[kk] = cospif(ph);  // step e^{+2*pi*i*t/1024}
    ss[kk] = sinpif(ph);
    wc[kk] = 1.0f;        // m = 0
    wsn[kk] = 0.0f;
  }

  float acc[2][8] = {{0.f}};
  for (int m = 0; m < 64; ++m) {
    float4 c0 = *reinterpret_cast<const float4*>(&Cr[m][j0]);
    float4 c1 = *reinterpret_cast<const float4*>(&Cr[m][j0 + 4]);
    float4 e0 = *reinterpret_cast<const float4*>(&Ci[m][j0]);
    float4 e1 = *reinterpret_cast<const float4*>(&Ci[m][j0 + 4]);
    float crv[8] = {c0.x, c0.y, c0.z, c0.w, c1.x, c1.y, c1.z, c1.w};
    float civ[8] = {e0.x, e0.y, e0.z, e0.w, e1.x, e1.y, e1.z, e1.w};
#pragma unroll
    for (int kk = 0; kk < 2; ++kk) {
      float cw = wc[kk], sw = wsn[kk];
#pragma unroll
      for (int jj = 0; jj < 8; ++jj) {
        acc[kk][jj] = fmaf(crv[jj], cw, acc[kk][jj]);
        acc[kk][jj] = fmaf(-civ[jj], sw, acc[kk][jj]);
      }
      float nr = cw * sc[kk] - sw * ss[kk];
      float ni = cw * ss[kk] + sw * sc[kk];
      wc[kk] = nr; wsn[kk] = ni;
    }
  }

#pragma unroll
  for (int jj = 0; jj < 8; ++jj) {
    *reinterpret_cast<float2*>(&out[(size_t)bh * 65536 + (size_t)(j0 + jj) * 1024 + t0]) =
        make_float2(acc[0][jj], acc[1][jj]);
  }
}

extern "C" void kernel_launch(void* const* d_in, const int* in_sizes, int n_in,
                              void* d_out, int out_size, void* d_ws, size_t ws_size,
                              hipStream_t stream) {
  const float* q   = (const float*)d_in[0];
  const float* k   = (const float*)d_in[1];
  // d_in[2] = value, unused by the reference forward
  const float* wre = (const float*)d_in[3];
  const float* wim = (const float*)d_in[4];
  float* out = (float*)d_out;
  float* ws  = (float*)d_ws;

  float* P   = ws;
  float* C1r = ws + C1R_OFF;
  float* C1i = ws + C1I_OFF;
  float* C2  = ws + C2_OFF;

  k_dft  <<<512,  256, 0, stream>>>(q, k, P);
  k_mid_a<<<256,  256, 0, stream>>>(P, C1r, C1i);
  k_mid_b<<<2048,  64, 0, stream>>>(C1r, C1i, wre, wim, C2);
  k_idft <<<1024, 256, 0, stream>>>(C2, out);
}

// Round 3
// 175.440 us; speedup vs baseline: 1.0879x; 1.0154x over previous
//
#include <hip/hip_runtime.h>
#include <hip/hip_bf16.h>
#include <cmath>

// Problem constants
#define BATCH 8
#define NH 8
#define BH 64          // BATCH*NH
#define SEQ 1024
#define DH 64          // head dim
#define NM 64          // modes

// ws layout (floats):
//  P   : [inp 2][tq 4][bh 64][c 2][m 64][d 64] = 4,194,304 floats
//  C1c : [bh 64][i 64][q 64][c 2]              =   524,288  (interleaved complex)
//  C2  : [bh 64][j 64][m 64][c 2]              =   524,288
// total 5.24M floats = 21.0 MB (same footprint as round 2 -> fits ws)
#define P_PLANE 4096   // 64m*64d
#define P_FLOATS (2*4*64*2*4096)
#define C1C_OFF  P_FLOATS
#define C2_OFF   (C1C_OFF + 64*64*64*2)

// ---------------------------------------------------------------------------
// Kernel 1: partial forward DFT. grid = (bh 64, input 2, t-quarter 4) = 512
// blocks x 256 thr = 8 waves/CU. Thread tile 2m x 8d: 8 LDS floats (2 b128)
// feed 32 fmaf -> LDS port ~49k cyc/CU ~ VALU ~44k cyc/SIMD (balanced), vs
// round-2's 1m x 16d which was port-bound at 98k cyc (measured 47us).
// ---------------------------------------------------------------------------
__global__ __launch_bounds__(256) void k_dft(const float* __restrict__ q,
                                             const float* __restrict__ k,
                                             float* __restrict__ P) {
  const int bid = blockIdx.x;
  const int bh = bid & 63;
  const int inp = (bid >> 6) & 1;
  const int tq = bid >> 7;  // 0..3, 256 samples each
  const float* x = (inp ? k : q) + (size_t)bh * (SEQ * DH);  // [t][d]

  __shared__ float xs[64][64];
  const int tid = threadIdx.x;
  const int mg = tid >> 3;      // 0..31 -> 2 modes each
  const int dg = tid & 7;       // 0..7  -> 8 d each
  const int m0 = mg * 2, d0 = dg * 8;

  float accr[2][8] = {{0.f}}, acci[2][8] = {{0.f}};

  // rotator step per mode: e^{-2*pi*i*m/1024}
  float stepc[2], steps[2];
#pragma unroll
  for (int mi = 0; mi < 2; ++mi) {
    float ph = (float)(m0 + mi) * (1.0f / 512.0f);
    stepc[mi] = cospif(ph);
    steps[mi] = -sinpif(ph);
  }

  for (int ch = 0; ch < 4; ++ch) {
    const int t0g = tq * 256 + ch * 64;
    const float4* src = reinterpret_cast<const float4*>(x + (size_t)t0g * DH);
    float4* dst = reinterpret_cast<float4*>(&xs[0][0]);
#pragma unroll
    for (int i = 0; i < 4; ++i) dst[tid + i * 256] = src[tid + i * 256];
    __syncthreads();

    // fresh twiddle at chunk start: e^{-2*pi*i*m*t0g/1024}
    float wr[2], wi[2];
#pragma unroll
    for (int mi = 0; mi < 2; ++mi) {
      int p0 = ((m0 + mi) * t0g) & 1023;
      float ph = (float)p0 * (1.0f / 512.0f);
      wr[mi] = cospif(ph);
      wi[mi] = -sinpif(ph);
    }

#pragma unroll 4
    for (int t = 0; t < 64; ++t) {
      float4 a = *reinterpret_cast<const float4*>(&xs[t][d0]);
      float4 b = *reinterpret_cast<const float4*>(&xs[t][d0 + 4]);
      float xv[8] = {a.x, a.y, a.z, a.w, b.x, b.y, b.z, b.w};
#pragma unroll
      for (int mi = 0; mi < 2; ++mi) {
        float cwr = wr[mi], cwi = wi[mi];
#pragma unroll
        for (int di = 0; di < 8; ++di) {
          accr[mi][di] = fmaf(cwr, xv[di], accr[mi][di]);
          acci[mi][di] = fmaf(cwi, xv[di], acci[mi][di]);
        }
        float nr = cwr * stepc[mi] - cwi * steps[mi];
        float ni = cwr * steps[mi] + cwi * stepc[mi];
        wr[mi] = nr; wi[mi] = ni;
      }
    }
    __syncthreads();
  }

  // P[inp][tq][bh][c][m][d]
  const size_t base = (((size_t)inp * 4 + tq) * 64 + bh) * 2 * P_PLANE;
#pragma unroll
  for (int mi = 0; mi < 2; ++mi) {
    float* pr = P + base + (size_t)(m0 + mi) * 64 + d0;
    float* pi = P + base + P_PLANE + (size_t)(m0 + mi) * 64 + d0;
    *reinterpret_cast<float4*>(pr) =
        make_float4(accr[mi][0], accr[mi][1], accr[mi][2], accr[mi][3]);
    *reinterpret_cast<float4*>(pr + 4) =
        make_float4(accr[mi][4], accr[mi][5], accr[mi][6], accr[mi][7]);
    *reinterpret_cast<float4*>(pi) =
        make_float4(acci[mi][0], acci[mi][1], acci[mi][2], acci[mi][3]);
    *reinterpret_cast<float4*>(pi + 4) =
        make_float4(acci[mi][4], acci[mi][5], acci[mi][6], acci[mi][7]);
  }
}

// stable complex tanh: tanh(x+iy) = (sinh2x + i sin2y)/(cosh2x + cos2y)
__device__ __forceinline__ void ctanh_f(float x, float y, float& rr, float& ri) {
  float a = 2.0f * x, b = 2.0f * y;
  if (fabsf(a) > 20.0f) {
    rr = (a > 0.0f) ? 1.0f : -1.0f;
    ri = 0.0f;
  } else {
    float ea = expf(a), ena = expf(-a);
    float sb, cb;
    sincosf(b, &sb, &cb);
    float den = 0.5f * (ea + ena) + cb;
    rr = 0.5f * (ea - ena) / den;
    ri = sb / den;
  }
}

// ---------------------------------------------------------------------------
// Kernel 2a: scores -> ctanh -> context -> C1. grid = (bh, q-quarter) = 256
// blocks. LDS rows padded to 68 floats (272 B, 16B-aligned) so both phases
// use ds_read_b128. Scores: thread = (q, k0) with k = k0+16j (consecutive
// lanes -> consecutive rows, 2-way banks = free). C1 out interleaved complex.
// ---------------------------------------------------------------------------
__global__ __launch_bounds__(256) void k_mid_a(const float* __restrict__ P,
                                               float* __restrict__ C1c) {
  __shared__ float Kr[64][68], Ki[64][68];
  __shared__ float Qr[16][68], Qi[16][68];
  __shared__ float Ar[16][68], Ai[16][68];
  __shared__ float C1rs[64][17], C1is[64][17];

  const int tid = threadIdx.x;
  const int bh = blockIdx.x >> 2;
  const int qq = blockIdx.x & 3;

  // P[inp][tq][bh][c][m][d]
  size_t pq[4], pk[4];
#pragma unroll
  for (int t = 0; t < 4; ++t) {
    pq[t] = (((size_t)(0 * 4 + t) * 64 + bh) * 2) * P_PLANE;
    pk[t] = (((size_t)(1 * 4 + t) * 64 + bh) * 2) * P_PLANE;
  }

  for (int idx = tid; idx < 4096; idx += 256) {
    int kk = idx >> 6, dd = idx & 63;
    float r = 0.f, im = 0.f;
#pragma unroll
    for (int t = 0; t < 4; ++t) {
      r += P[pk[t] + idx];
      im += P[pk[t] + P_PLANE + idx];
    }
    Kr[kk][dd] = r; Ki[kk][dd] = im;
  }
  for (int idx = tid; idx < 1024; idx += 256) {
    int qi2 = idx >> 6, dd = idx & 63;
    int mm = qq * 16 + qi2;
    float r = 0.f, im = 0.f;
#pragma unroll
    for (int t = 0; t < 4; ++t) {
      r += P[pq[t] + mm * 64 + dd];
      im += P[pq[t] + P_PLANE + mm * 64 + dd];
    }
    Qr[qi2][dd] = r; Qi[qi2][dd] = im;
  }
  __syncthreads();

  // scores S[q][k] = sum_d Q[q][d]*K[k][d] (complex, no conj) -> ctanh
  {
    const int q = tid >> 4, k0 = tid & 15;
    float sr[4] = {0.f}, si[4] = {0.f};
    for (int d = 0; d < 64; d += 4) {
      const float4 qr = *reinterpret_cast<const float4*>(&Qr[q][d]);
      const float4 qi = *reinterpret_cast<const float4*>(&Qi[q][d]);
#pragma unroll
      for (int j = 0; j < 4; ++j) {
        const int kk = k0 + 16 * j;
        const float4 kr = *reinterpret_cast<const float4*>(&Kr[kk][d]);
        const float4 ki = *reinterpret_cast<const float4*>(&Ki[kk][d]);
        float s0 = sr[j], s1 = si[j];
        s0 = fmaf(qr.x, kr.x, s0); s0 = fmaf(-qi.x, ki.x, s0);
        s1 = fmaf(qr.x, ki.x, s1); s1 = fmaf(qi.x, kr.x, s1);
        s0 = fmaf(qr.y, kr.y, s0); s0 = fmaf(-qi.y, ki.y, s0);
        s1 = fmaf(qr.y, ki.y, s1); s1 = fmaf(qi.y, kr.y, s1);
        s0 = fmaf(qr.z, kr.z, s0); s0 = fmaf(-qi.z, ki.z, s0);
        s1 = fmaf(qr.z, ki.z, s1); s1 = fmaf(qi.z, kr.z, s1);
        s0 = fmaf(qr.w, kr.w, s0); s0 = fmaf(-qi.w, ki.w, s0);
        s1 = fmaf(qr.w, ki.w, s1); s1 = fmaf(qi.w, kr.w, s1);
        sr[j] = s0; si[j] = s1;
      }
    }
#pragma unroll
    for (int j = 0; j < 4; ++j) {
      float rr, ri;
      ctanh_f(sr[j], si[j], rr, ri);
      Ar[q][k0 + 16 * j] = rr;
      Ai[q][k0 + 16 * j] = ri;
    }
  }
  __syncthreads();

  // C1[d][q] = sum_k A[q][k]*K[k][d]
  {
    const int q = tid >> 4, d0 = (tid & 15) * 4;
    float cr[4] = {0.f}, ci[4] = {0.f};
    for (int kk = 0; kk < 64; ++kk) {
      float ar = Ar[q][kk], ai = Ai[q][kk];
      const float4 kr = *reinterpret_cast<const float4*>(&Kr[kk][d0]);
      const float4 ki = *reinterpret_cast<const float4*>(&Ki[kk][d0]);
      cr[0] = fmaf(ar, kr.x, cr[0]); cr[0] = fmaf(-ai, ki.x, cr[0]);
      ci[0] = fmaf(ar, ki.x, ci[0]); ci[0] = fmaf(ai, kr.x, ci[0]);
      cr[1] = fmaf(ar, kr.y, cr[1]); cr[1] = fmaf(-ai, ki.y, cr[1]);
      ci[1] = fmaf(ar, ki.y, ci[1]); ci[1] = fmaf(ai, kr.y, ci[1]);
      cr[2] = fmaf(ar, kr.z, cr[2]); cr[2] = fmaf(-ai, ki.z, cr[2]);
      ci[2] = fmaf(ar, ki.z, ci[2]); ci[2] = fmaf(ai, kr.z, ci[2]);
      cr[3] = fmaf(ar, kr.w, cr[3]); cr[3] = fmaf(-ai, ki.w, cr[3]);
      ci[3] = fmaf(ar, ki.w, ci[3]); ci[3] = fmaf(ai, kr.w, ci[3]);
    }
#pragma unroll
    for (int j = 0; j < 4; ++j) { C1rs[d0 + j][tid >> 4] = cr[j]; C1is[d0 + j][tid >> 4] = ci[j]; }
  }
  __syncthreads();

  // write C1c[bh][i][qglobal][2], interleaved complex, coalesced
  for (int idx = tid; idx < 1024; idx += 256) {
    int i = idx >> 4, ql = idx & 15;
    size_t o = (((size_t)bh * 64 + i) * 64 + qq * 16 + ql) * 2;
    *reinterpret_cast<float2*>(&C1c[o]) = make_float2(C1rs[i][ql], C1is[i][ql]);
  }
}

// ---------------------------------------------------------------------------
// Kernel 2b: C2[b,h,j,q] = sum_i C1[b,h,i,q] * (wre+i*wim)[h,i,j,q]
// lane = q -> w loads 256B coalesced; C1 float2 loads 512B coalesced.
// grid = (h 8, j 64, b-quarter 4) = 2048 one-wave blocks = 8 waves/CU.
// ---------------------------------------------------------------------------
__global__ __launch_bounds__(64) void k_mid_b(const float* __restrict__ C1c,
                                              const float* __restrict__ wre,
                                              const float* __restrict__ wim,
                                              float* __restrict__ C2) {
  const int bid = blockIdx.x;
  const int j = bid & 63;
  const int h = (bid >> 6) & 7;
  const int bq = bid >> 9;
  const int lane = threadIdx.x;  // q

  const int bh0 = (bq * 2 + 0) * 8 + h;
  const int bh1 = (bq * 2 + 1) * 8 + h;
  const float2* c1a = reinterpret_cast<const float2*>(C1c) + (size_t)bh0 * 4096 + lane;
  const float2* c1b = reinterpret_cast<const float2*>(C1c) + (size_t)bh1 * 4096 + lane;
  const float* wrp = wre + ((size_t)h * 4096 + j) * 64 + lane;
  const float* wip = wim + ((size_t)h * 4096 + j) * 64 + lane;

  float ar0 = 0.f, ai0 = 0.f, ar1 = 0.f, ai1 = 0.f;
#pragma unroll 8
  for (int i = 0; i < 64; ++i) {
    float wr = wrp[(size_t)i * 4096];
    float wi = wip[(size_t)i * 4096];
    float2 ca = c1a[(size_t)i * 64];
    float2 cb = c1b[(size_t)i * 64];
    ar0 = fmaf(ca.x, wr, ar0); ar0 = fmaf(-ca.y, wi, ar0);
    ai0 = fmaf(ca.x, wi, ai0); ai0 = fmaf(ca.y, wr, ai0);
    ar1 = fmaf(cb.x, wr, ar1); ar1 = fmaf(-cb.y, wi, ar1);
    ai1 = fmaf(cb.x, wi, ai1); ai1 = fmaf(cb.y, wr, ai1);
  }
  // C2[bh][j][m][2]
  *reinterpret_cast<float2*>(&C2[(((size_t)bh0 * 64 + j) * 64 + lane) * 2]) = make_float2(ar0, ai0);
  *reinterpret_cast<float2*>(&C2[(((size_t)bh1 * 64 + j) * 64 + lane) * 2]) = make_float2(ar1, ai1);
}

// ---------------------------------------------------------------------------
// Kernel 3: inverse partial DFT. grid = (bh, 8 t-chunks of 128) = 512 blocks
// = 8 waves/CU. Thread tile 4t x 8j: the 16 LDS floats per m now feed 64 fmaf
// (round-2's 2t x 8j fed only 32 -> was port-bound at ~20us).
// ---------------------------------------------------------------------------
__global__ __launch_bounds__(256) void k_idft(const float* __restrict__ C2,
                                              float* __restrict__ out) {
  __shared__ float Cr[64][68], Ci[64][68];
  const int tid = threadIdx.x;
  const int bh = blockIdx.x >> 3;
  const int tc = blockIdx.x & 7;
  const float s = 1.0f / (512.0f * 512.0f * 1024.0f);

  for (int idx = tid; idx < 4096; idx += 256) {
    int j = idx >> 6, m = idx & 63;
    float f = (m == 0) ? s : 2.0f * s;
    float2 c = *reinterpret_cast<const float2*>(&C2[(((size_t)bh * 64 + j) * 64 + m) * 2]);
    Cr[m][j] = f * c.x;
    Ci[m][j] = f * c.y;
  }
  __syncthreads();

  const int tg = tid & 31, jg = tid >> 5;
  const int t0 = tc * 128 + tg * 4, j0 = jg * 8;

  float sc[4], ss[4], wc[4], wsn[4];
#pragma unroll
  for (int kk = 0; kk < 4; ++kk) {
    float ph = (float)((t0 + kk) & 1023) * (1.0f / 512.0f);
    sc[kk] = cospif(ph);  // step e^{+2*pi*i*t/1024}
    ss[kk] = sinpif(ph);
    wc[kk] = 1.0f;        // m = 0
    wsn[kk] = 0.0f;
  }

  float acc[4][8] = {{0.f}};
  for (int m = 0; m < 64; ++m) {
    float4 c0 = *reinterpret_cast<const float4*>(&Cr[m][j0]);
    float4 c1 = *reinterpret_cast<const float4*>(&Cr[m][j0 + 4]);
    float4 e0 = *reinterpret_cast<const float4*>(&Ci[m][j0]);
    float4 e1 = *reinterpret_cast<const float4*>(&Ci[m][j0 + 4]);
    float crv[8] = {c0.x, c0.y, c0.z, c0.w, c1.x, c1.y, c1.z, c1.w};
    float civ[8] = {e0.x, e0.y, e0.z, e0.w, e1.x, e1.y, e1.z, e1.w};
#pragma unroll
    for (int kk = 0; kk < 4; ++kk) {
      float cw = wc[kk], sw = wsn[kk];
#pragma unroll
      for (int jj = 0; jj < 8; ++jj) {
        acc[kk][jj] = fmaf(crv[jj], cw, acc[kk][jj]);
        acc[kk][jj] = fmaf(-civ[jj], sw, acc[kk][jj]);
      }
      float nr = cw * sc[kk] - sw * ss[kk];
      float ni = cw * ss[kk] + sw * sc[kk];
      wc[kk] = nr; wsn[kk] = ni;
    }
  }

#pragma unroll
  for (int jj = 0; jj < 8; ++jj) {
    *reinterpret_cast<float4*>(&out[(size_t)bh * 65536 + (size_t)(j0 + jj) * 1024 + t0]) =
        make_float4(acc[0][jj], acc[1][jj], acc[2][jj], acc[3][jj]);
  }
}

extern "C" void kernel_launch(void* const* d_in, const int* in_sizes, int n_in,
                              void* d_out, int out_size, void* d_ws, size_t ws_size,
                              hipStream_t stream) {
  const float* q   = (const float*)d_in[0];
  const float* k   = (const float*)d_in[1];
  // d_in[2] = value, unused by the reference forward
  const float* wre = (const float*)d_in[3];
  const float* wim = (const float*)d_in[4];
  float* out = (float*)d_out;
  float* ws  = (float*)d_ws;

  float* P   = ws;
  float* C1c = ws + C1C_OFF;
  float* C2  = ws + C2_OFF;

  k_dft  <<<512,  256, 0, stream>>>(q, k, P);
  k_mid_a<<<256,  256, 0, stream>>>(P, C1c);
  k_mid_b<<<2048,  64, 0, stream>>>(C1c, wre, wim, C2);
  k_idft <<<512,  256, 0, stream>>>(C2, out);
}